// Round 2
// baseline (432.344 us; speedup 1.0000x reference)
//
#include <hip/hip_runtime.h>
#include <cstdint>
#include <cstddef>

// ---------- types / helpers ----------
typedef __bf16 bf16x8 __attribute__((ext_vector_type(8)));
typedef float  f32x4  __attribute__((ext_vector_type(4)));

#define DEV static __device__ __forceinline__

DEV unsigned short f2bf(float f) {
    unsigned int u = __builtin_bit_cast(unsigned int, f);
    u += 0x7FFFu + ((u >> 16) & 1u);   // round-to-nearest-even
    return (unsigned short)(u >> 16);
}
DEV float bf2f(unsigned short h) {
    unsigned int u = ((unsigned int)h) << 16;
    return __builtin_bit_cast(float, u);
}

// ---------- problem constants ----------
#define BB 4
#define TT 2048
#define CC 768
#define NH 12
#define DH 64
#define MM (BB*TT)          // 8192

// ---------- transpose f32 -> bf16: dst[Cc][R] = bf16(src[R][Cc]) ----------
__global__ __launch_bounds__(256)
void transpose_k(const float* __restrict__ src,
                 unsigned short* __restrict__ dst, int R, int Cc)
{
    __shared__ float tile[32][33];
    int c0 = blockIdx.x * 32, r0 = blockIdx.y * 32;
    int tx = threadIdx.x, ty = threadIdx.y;
#pragma unroll
    for (int i = 0; i < 4; ++i)
        tile[ty + i*8][tx] = src[(size_t)(r0 + ty + i*8) * Cc + c0 + tx];
    __syncthreads();
#pragma unroll
    for (int i = 0; i < 4; ++i)
        dst[(size_t)(c0 + ty + i*8) * R + r0 + tx] = f2bf(tile[tx][ty + i*8]);
}

// ---------- GEMM: C[M,N] = A[M,K] * Bt[N,K]^T + bias[N] ----------
// MODE 0: A is bf16, store f32 to Cout[M*N]
// MODE 1: A is f32 (converted to bf16 at staging), scatter qkv -> Qo/Ko/Vo
//         in [B,H,T,Dh] bf16, Q scaled by 0.125
#define BM 128
#define BN 128
#define BK 32
#define LSTR 56   // LDS row stride (elements): 112 B rows -> 16B aligned, 2-way banks (free)

template<int MODE>
__global__ __launch_bounds__(256)
void gemm_bt(const void* __restrict__ Av,
             const unsigned short* __restrict__ Bt,
             const float* __restrict__ bias,
             float* __restrict__ Cout,
             unsigned short* __restrict__ Qo,
             unsigned short* __restrict__ Ko,
             unsigned short* __restrict__ Vo,
             int M, int N, int K)
{
    __shared__ __align__(16) unsigned short As[BM * LSTR];
    __shared__ __align__(16) unsigned short Bs[BN * LSTR];

    const int tid  = threadIdx.x;
    const int wave = tid >> 6, lane = tid & 63;
    const int quad = lane >> 4, l16 = lane & 15;
    const int waveM = (wave >> 1) * 64, waveN = (wave & 1) * 64;
    const int m0 = blockIdx.y * BM, n0 = blockIdx.x * BN;

    const f32x4 zero4 = {0.f, 0.f, 0.f, 0.f};
    f32x4 acc[4][4];
#pragma unroll
    for (int i = 0; i < 4; ++i)
#pragma unroll
        for (int j = 0; j < 4; ++j) acc[i][j] = zero4;

    const int nk = K / BK;
    for (int kt = 0; kt < nk; ++kt) {
        // stage tiles: 128x32 elements = 512 chunks of 8 elems, 2 per thread
#pragma unroll
        for (int i = 0; i < 2; ++i) {
            int idx = tid + i * 256;
            int row = idx >> 2, cc = (idx & 3) * 8;
            if (MODE == 1) {
                const float* A = (const float*)Av;
                const float4* p = reinterpret_cast<const float4*>(A + (size_t)(m0 + row) * K + kt * BK + cc);
                float4 f0 = p[0], f1 = p[1];
                union { uint4 u; unsigned short s[8]; } cv;
                cv.s[0] = f2bf(f0.x); cv.s[1] = f2bf(f0.y);
                cv.s[2] = f2bf(f0.z); cv.s[3] = f2bf(f0.w);
                cv.s[4] = f2bf(f1.x); cv.s[5] = f2bf(f1.y);
                cv.s[6] = f2bf(f1.z); cv.s[7] = f2bf(f1.w);
                *reinterpret_cast<uint4*>(&As[row * LSTR + cc]) = cv.u;
            } else {
                const unsigned short* A = (const unsigned short*)Av;
                uint4 va = *reinterpret_cast<const uint4*>(A + (size_t)(m0 + row) * K + kt * BK + cc);
                *reinterpret_cast<uint4*>(&As[row * LSTR + cc]) = va;
            }
            uint4 vb = *reinterpret_cast<const uint4*>(Bt + (size_t)(n0 + row) * K + kt * BK + cc);
            *reinterpret_cast<uint4*>(&Bs[row * LSTR + cc]) = vb;
        }
        __syncthreads();

        bf16x8 af[4], bfv[4];
#pragma unroll
        for (int mi = 0; mi < 4; ++mi)
            af[mi] = *reinterpret_cast<const bf16x8*>(&As[(waveM + mi * 16 + l16) * LSTR + quad * 8]);
#pragma unroll
        for (int ni = 0; ni < 4; ++ni)
            bfv[ni] = *reinterpret_cast<const bf16x8*>(&Bs[(waveN + ni * 16 + l16) * LSTR + quad * 8]);
#pragma unroll
        for (int mi = 0; mi < 4; ++mi)
#pragma unroll
            for (int ni = 0; ni < 4; ++ni)
                acc[mi][ni] = __builtin_amdgcn_mfma_f32_16x16x32_bf16(af[mi], bfv[ni], acc[mi][ni], 0, 0, 0);
        __syncthreads();
    }

    // epilogue: C/D layout col = lane&15, row = quad*4 + reg
#pragma unroll
    for (int mi = 0; mi < 4; ++mi) {
#pragma unroll
        for (int ni = 0; ni < 4; ++ni) {
            int n = n0 + waveN + ni * 16 + l16;
            float bv = bias[n];
#pragma unroll
            for (int reg = 0; reg < 4; ++reg) {
                int m = m0 + waveM + mi * 16 + quad * 4 + reg;
                float v = acc[mi][ni][reg] + bv;
                if (MODE == 0) {
                    Cout[(size_t)m * N + n] = v;
                } else {
                    int which = n / CC, c2 = n % CC;
                    int h = c2 >> 6, d = c2 & 63;
                    int b = m >> 11, t = m & 2047;
                    size_t off = ((size_t)(b * NH + h) * TT + t) * DH + d;
                    if (which == 0)      Qo[off] = f2bf(v * 0.125f);
                    else if (which == 1) Ko[off] = f2bf(v);
                    else                 Vo[off] = f2bf(v);
                }
            }
        }
    }
}

// ---------- flash attention (causal), 64-row q-tile per block, 4 waves ----------
#define AST 72   // LDS row stride for 64-wide rows: 144 B, 16B aligned

__global__ __launch_bounds__(256)
void attn_k(const unsigned short* __restrict__ Qg,
            const unsigned short* __restrict__ Kg,
            const unsigned short* __restrict__ Vg,
            unsigned short* __restrict__ Og)
{
    __shared__ __align__(16) unsigned short Qs[64 * AST];       // [m][d]
    __shared__ __align__(16) unsigned short Ks[64 * AST];       // [key][d]
    __shared__ __align__(16) unsigned short Vs[64 * AST];       // transposed: [d][key]
    __shared__ __align__(16) unsigned short Ps[4][16 * AST];    // per-wave [m][key]

    const int tid  = threadIdx.x;
    const int wave = tid >> 6, lane = tid & 63;
    const int quad = lane >> 4, l16 = lane & 15;
    const int q0 = blockIdx.x * 64;
    const int bh = blockIdx.y;                    // b*NH + h
    const size_t base = (size_t)bh * TT * DH;

    // stage Q tile (64x64)
#pragma unroll
    for (int i = 0; i < 2; ++i) {
        int idx = tid + i * 256;
        int row = idx >> 3, c = (idx & 7) * 8;
        *reinterpret_cast<uint4*>(&Qs[row * AST + c]) =
            *reinterpret_cast<const uint4*>(Qg + base + (size_t)(q0 + row) * DH + c);
    }

    const f32x4 zero4 = {0.f, 0.f, 0.f, 0.f};
    f32x4 o[4];
#pragma unroll
    for (int i = 0; i < 4; ++i) o[i] = zero4;
    float mrow[4] = {-INFINITY, -INFINITY, -INFINITY, -INFINITY};
    float lrow[4] = {0.f, 0.f, 0.f, 0.f};

    const int nkt = blockIdx.x + 1;               // causal: key tiles 0..qtile
    for (int j = 0; j < nkt; ++j) {
        __syncthreads();  // previous iteration done with Ks/Vs (also orders Q staging)
#pragma unroll
        for (int i = 0; i < 2; ++i) {
            int idx = tid + i * 256;
            int row = idx >> 3, c = (idx & 7) * 8;
            *reinterpret_cast<uint4*>(&Ks[row * AST + c]) =
                *reinterpret_cast<const uint4*>(Kg + base + (size_t)(j * 64 + row) * DH + c);
            union { uint4 u; unsigned short s[8]; } uv;
            uv.u = *reinterpret_cast<const uint4*>(Vg + base + (size_t)(j * 64 + row) * DH + c);
#pragma unroll
            for (int e = 0; e < 8; ++e) Vs[(c + e) * AST + row] = uv.s[e];  // transpose
        }
        __syncthreads();

        // S = Q K^T  (scale already folded into Q)
        bf16x8 aq0 = *reinterpret_cast<const bf16x8*>(&Qs[(wave * 16 + l16) * AST + quad * 8]);
        bf16x8 aq1 = *reinterpret_cast<const bf16x8*>(&Qs[(wave * 16 + l16) * AST + 32 + quad * 8]);
        f32x4 s[4];
#pragma unroll
        for (int sub = 0; sub < 4; ++sub) {
            bf16x8 bk0 = *reinterpret_cast<const bf16x8*>(&Ks[(sub * 16 + l16) * AST + quad * 8]);
            bf16x8 bk1 = *reinterpret_cast<const bf16x8*>(&Ks[(sub * 16 + l16) * AST + 32 + quad * 8]);
            s[sub] = __builtin_amdgcn_mfma_f32_16x16x32_bf16(aq0, bk0, zero4, 0, 0, 0);
            s[sub] = __builtin_amdgcn_mfma_f32_16x16x32_bf16(aq1, bk1, s[sub], 0, 0, 0);
        }

        // causal mask + online softmax (rows = quad*4+reg, cols = sub*16+l16)
        const int qrow_base = q0 + wave * 16 + quad * 4;
#pragma unroll
        for (int reg = 0; reg < 4; ++reg) {
            int qidx = qrow_base + reg;
            float mx = -INFINITY;
#pragma unroll
            for (int sub = 0; sub < 4; ++sub) {
                int kidx = j * 64 + sub * 16 + l16;
                float sv = (kidx <= qidx) ? s[sub][reg] : -INFINITY;
                s[sub][reg] = sv;
                mx = fmaxf(mx, sv);
            }
#pragma unroll
            for (int off = 1; off < 16; off <<= 1)
                mx = fmaxf(mx, __shfl_xor(mx, off, 64));
            float mnew  = fmaxf(mrow[reg], mx);
            float alpha = __expf(mrow[reg] - mnew);   // exp(-inf)=0 on first tile
            float rs = 0.f;
#pragma unroll
            for (int sub = 0; sub < 4; ++sub) {
                float pv = __expf(s[sub][reg] - mnew); // masked -> exp(-inf)=0
                rs += pv;
                Ps[wave][(quad * 4 + reg) * AST + sub * 16 + l16] = f2bf(pv);
            }
#pragma unroll
            for (int off = 1; off < 16; off <<= 1)
                rs += __shfl_xor(rs, off, 64);
            lrow[reg] = lrow[reg] * alpha + rs;
            mrow[reg] = mnew;
#pragma unroll
            for (int sub = 0; sub < 4; ++sub)
                o[sub][reg] *= alpha;
        }
        __syncthreads();  // Vs/Ks safe to overwrite next iter only after PV below? (barrier also orders Ps for consistency)

        // O += P V : A-frag from Ps, B-frag from Vs (transposed layout)
#pragma unroll
        for (int kc = 0; kc < 2; ++kc) {
            bf16x8 ap = *reinterpret_cast<const bf16x8*>(&Ps[wave][l16 * AST + kc * 32 + quad * 8]);
#pragma unroll
            for (int sub = 0; sub < 4; ++sub) {
                bf16x8 bv = *reinterpret_cast<const bf16x8*>(&Vs[(sub * 16 + l16) * AST + kc * 32 + quad * 8]);
                o[sub] = __builtin_amdgcn_mfma_f32_16x16x32_bf16(ap, bv, o[sub], 0, 0, 0);
            }
        }
    }

    // epilogue: write att in [B,T,C] layout (C = h*64 + d), bf16
    const int b = bh / NH, h = bh % NH;
#pragma unroll
    for (int sub = 0; sub < 4; ++sub) {
#pragma unroll
        for (int reg = 0; reg < 4; ++reg) {
            int t = q0 + wave * 16 + quad * 4 + reg;
            int d = sub * 16 + l16;
            float val = o[sub][reg] / lrow[reg];
            Og[((size_t)(b * TT + t)) * CC + h * DH + d] = f2bf(val);
        }
    }
}

// ---------- launch ----------
extern "C" void kernel_launch(void* const* d_in, const int* in_sizes, int n_in,
                              void* d_out, int out_size, void* d_ws, size_t ws_size,
                              hipStream_t stream)
{
    const float* x      = (const float*)d_in[0];
    const float* w_attn = (const float*)d_in[1];
    const float* b_attn = (const float*)d_in[2];
    const float* w_proj = (const float*)d_in[3];
    const float* b_proj = (const float*)d_in[4];
    float* out = (float*)d_out;

    char* ws = (char*)d_ws;
    size_t off = 0;
    auto alloc = [&](size_t bytes) {
        void* p = ws + off;
        off += (bytes + 255) & ~(size_t)255;
        return p;
    };
    unsigned short* wtA = (unsigned short*)alloc((size_t)(3 * CC) * CC * 2);  // [2304][768] bf16
    unsigned short* wtP = (unsigned short*)alloc((size_t)CC * CC * 2);        // [768][768]  bf16
    unsigned short* Qb  = (unsigned short*)alloc((size_t)MM * DH * NH * 2);   // [B,H,T,Dh]  bf16
    unsigned short* Kb  = (unsigned short*)alloc((size_t)MM * DH * NH * 2);
    unsigned short* Vb  = (unsigned short*)alloc((size_t)MM * DH * NH * 2);
    unsigned short* att = (unsigned short*)alloc((size_t)MM * CC * 2);        // [B,T,C] bf16

    // 1) transpose weights (f32 -> bf16)
    transpose_k<<<dim3((3 * CC) / 32, CC / 32), dim3(32, 8), 0, stream>>>(w_attn, wtA, CC, 3 * CC);
    transpose_k<<<dim3(CC / 32, CC / 32), dim3(32, 8), 0, stream>>>(w_proj, wtP, CC, CC);

    // 2) qkv = x @ w_attn + b_attn, scatter to Q(scaled)/K/V
    gemm_bt<1><<<dim3((3 * CC) / BN, MM / BM), 256, 0, stream>>>(
        x, wtA, b_attn, nullptr, Qb, Kb, Vb, MM, 3 * CC, CC);

    // 3) causal flash attention
    attn_k<<<dim3(TT / 64, BB * NH), 256, 0, stream>>>(Qb, Kb, Vb, att);

    // 4) out = att @ w_proj + b_proj (f32 out)
    gemm_bt<0><<<dim3(CC / BN, MM / BM), 256, 0, stream>>>(
        att, wtP, b_proj, out, nullptr, nullptr, nullptr, MM, CC, CC);

    (void)in_sizes; (void)n_in; (void)out_size; (void)ws_size;
}

// Round 3
// 319.585 us; speedup vs baseline: 1.3528x; 1.3528x over previous
//
#include <hip/hip_runtime.h>
#include <cstdint>
#include <cstddef>

// ---------- types / helpers ----------
typedef __bf16 bf16x8 __attribute__((ext_vector_type(8)));
typedef float  f32x4  __attribute__((ext_vector_type(4)));
typedef unsigned short us;

#define DEV static __device__ __forceinline__

DEV us f2bf(float f) {
    unsigned int u = __builtin_bit_cast(unsigned int, f);
    u += 0x7FFFu + ((u >> 16) & 1u);   // RNE
    return (us)(u >> 16);
}

DEV void gll16(const void* g, void* l) {   // 16B global->LDS direct (wave: +lane*16)
    __builtin_amdgcn_global_load_lds(
        (const __attribute__((address_space(1))) unsigned int*)g,
        (__attribute__((address_space(3))) unsigned int*)l, 16, 0, 0);
}

// ---------- problem constants ----------
#define BB 4
#define TT 2048
#define CC 768
#define NH 12
#define DH 64
#define MM (BB*TT)          // 8192
#define QSCALE 0.1803368801111144f   // 0.125 * log2(e): softmax via exp2

// ---------- cast f32 -> bf16 ----------
__global__ __launch_bounds__(256)
void cast_k(const float* __restrict__ x, us* __restrict__ xb, int n4)
{
    int i = blockIdx.x * 256 + threadIdx.x;
    int stride = gridDim.x * 256;
    for (; i < n4; i += stride) {
        float4 f = reinterpret_cast<const float4*>(x)[i];
        ushort4 o;
        o.x = f2bf(f.x); o.y = f2bf(f.y); o.z = f2bf(f.z); o.w = f2bf(f.w);
        reinterpret_cast<ushort4*>(xb)[i] = o;
    }
}

// ---------- transpose f32 -> bf16: dst[Cc][R] = bf16(src[R][Cc]) ----------
__global__ __launch_bounds__(256)
void transpose_k(const float* __restrict__ src,
                 us* __restrict__ dst, int R, int Cc)
{
    __shared__ float tile[32][33];
    int c0 = blockIdx.x * 32, r0 = blockIdx.y * 32;
    int tx = threadIdx.x, ty = threadIdx.y;
#pragma unroll
    for (int i = 0; i < 4; ++i)
        tile[ty + i*8][tx] = src[(size_t)(r0 + ty + i*8) * Cc + c0 + tx];
    __syncthreads();
#pragma unroll
    for (int i = 0; i < 4; ++i)
        dst[(size_t)(c0 + ty + i*8) * R + r0 + tx] = f2bf(tile[tx][ty + i*8]);
}

// ---------- GEMM: C[M,N] = A[M,K](bf16) * Bt[N,K]^T + bias[N] ----------
// MODE 0: store f32 to Cout;  MODE 1: scatter qkv -> Qo(scaled)/Ko/Vo [B,H,T,Dh] bf16
#define BM 128
#define BN 128
#define BK 32

template<int MODE>
__global__ __launch_bounds__(256)
void gemm_bt(const us* __restrict__ A,
             const us* __restrict__ Bt,
             const float* __restrict__ bias,
             float* __restrict__ Cout,
             us* __restrict__ Qo, us* __restrict__ Ko, us* __restrict__ Vo,
             int M, int N, int K)
{
    __shared__ __align__(16) us As[BM * BK];
    __shared__ __align__(16) us Bs[BN * BK];

    const int tid  = threadIdx.x;
    const int wave = tid >> 6, lane = tid & 63;
    const int quad = lane >> 4, l16 = lane & 15;
    const int waveM = (wave >> 1) * 64, waveN = (wave & 1) * 64;
    const int m0 = blockIdx.y * BM, n0 = blockIdx.x * BN;

    const f32x4 zero4 = {0.f, 0.f, 0.f, 0.f};
    f32x4 acc[4][4];
#pragma unroll
    for (int i = 0; i < 4; ++i)
#pragma unroll
        for (int j = 0; j < 4; ++j) acc[i][j] = zero4;

    const int lrow = lane >> 2, lch = (lane & 3) * 8;
    const int nk = K / BK;
    for (int kt = 0; kt < nk; ++kt) {
        // stage via global_load_lds width=16; lane i -> lds base + i*16B
#pragma unroll
        for (int c = 0; c < 2; ++c) {
            int rb = (wave * 2 + c) * 16;          // 16-row group
            int row = rb + lrow;
            gll16(A  + (size_t)(m0 + row) * K + kt * BK + lch, &As[rb * BK]);
            gll16(Bt + (size_t)(n0 + row) * K + kt * BK + lch, &Bs[rb * BK]);
        }
        __syncthreads();

        bf16x8 af[4], bfv[4];
#pragma unroll
        for (int mi = 0; mi < 4; ++mi)
            af[mi] = *reinterpret_cast<const bf16x8*>(&As[(waveM + mi * 16 + l16) * BK + quad * 8]);
#pragma unroll
        for (int ni = 0; ni < 4; ++ni)
            bfv[ni] = *reinterpret_cast<const bf16x8*>(&Bs[(waveN + ni * 16 + l16) * BK + quad * 8]);
#pragma unroll
        for (int mi = 0; mi < 4; ++mi)
#pragma unroll
            for (int ni = 0; ni < 4; ++ni)
                acc[mi][ni] = __builtin_amdgcn_mfma_f32_16x16x32_bf16(af[mi], bfv[ni], acc[mi][ni], 0, 0, 0);
        __syncthreads();
    }

    // epilogue: C/D layout col = l16, row = quad*4 + reg
#pragma unroll
    for (int mi = 0; mi < 4; ++mi) {
#pragma unroll
        for (int ni = 0; ni < 4; ++ni) {
            int n = n0 + waveN + ni * 16 + l16;
            float bv = bias[n];
#pragma unroll
            for (int reg = 0; reg < 4; ++reg) {
                int m = m0 + waveM + mi * 16 + quad * 4 + reg;
                float v = acc[mi][ni][reg] + bv;
                if (MODE == 0) {
                    Cout[(size_t)m * N + n] = v;
                } else {
                    int which = n / CC, c2 = n % CC;
                    int h = c2 >> 6, d = c2 & 63;
                    int b = m >> 11, t = m & 2047;
                    size_t off = ((size_t)(b * NH + h) * TT + t) * DH + d;
                    if (which == 0)      Qo[off] = f2bf(v * QSCALE);
                    else if (which == 1) Ko[off] = f2bf(v);
                    else                 Vo[off] = f2bf(v);
                }
            }
        }
    }
}

// ---------- flash attention (causal), S^T layout: one query per lane ----------
#define KST 72   // Ks/Vs row stride (shorts)
#define PST 72   // Ps row stride

__global__ __launch_bounds__(256, 4)
void attn_k(const us* __restrict__ Qg,
            const us* __restrict__ Kg,
            const us* __restrict__ Vg,
            us* __restrict__ Og)
{
    __shared__ __align__(16) us Ks[64 * KST];        // [key][d]
    __shared__ __align__(16) us Vs[64 * KST];        // [d][key] (transposed)
    __shared__ __align__(16) us Ps[4][16 * PST];     // per-wave [m][key]

    const int tid  = threadIdx.x;
    const int wave = tid >> 6, lane = tid & 63;
    const int quad = lane >> 4, l16 = lane & 15;
    const int qt = (int)gridDim.x - 1 - (int)blockIdx.x;   // LPT: longest first
    const int q0 = qt * 64;
    const int bh = blockIdx.y;
    const size_t base = (size_t)bh * TT * DH;

    const int m = q0 + wave * 16 + l16;   // this lane's query row

    // Q fragments in registers (B-operand: [m][k])
    bf16x8 qf0 = __builtin_bit_cast(bf16x8,
        *reinterpret_cast<const uint4*>(Qg + base + (size_t)m * DH + quad * 8));
    bf16x8 qf1 = __builtin_bit_cast(bf16x8,
        *reinterpret_cast<const uint4*>(Qg + base + (size_t)m * DH + 32 + quad * 8));

    // K prefetch mapping: row = idx>>3, chunk = (idx&7)*8 (coalesced)
    // V prefetch mapping: row = idx&63, chunk = (idx>>6)*8 (per-lane row -> conflict-free LDS transpose)
    uint4 kpre[2], vpre[2];
    {
        const int j = 0;
#pragma unroll
        for (int i = 0; i < 2; ++i) {
            int idx = tid + i * 256;
            kpre[i] = *reinterpret_cast<const uint4*>(Kg + base + (size_t)(j * 64 + (idx >> 3)) * DH + (idx & 7) * 8);
            vpre[i] = *reinterpret_cast<const uint4*>(Vg + base + (size_t)(j * 64 + (idx & 63)) * DH + (idx >> 6) * 8);
        }
    }

    const f32x4 zero4 = {0.f, 0.f, 0.f, 0.f};
    f32x4 o[4];   // O^T: d = dsub*16 + quad*4 + reg, col m = l16
#pragma unroll
    for (int i = 0; i < 4; ++i) o[i] = zero4;
    float mrow = -INFINITY, lrow = 0.f;

    const int nkt = qt + 1;
    for (int j = 0; j < nkt; ++j) {
        __syncthreads();   // all waves done with previous tile's LDS
        // commit prefetched tile j to LDS
#pragma unroll
        for (int i = 0; i < 2; ++i) {
            int idx = tid + i * 256;
            *reinterpret_cast<uint4*>(&Ks[(idx >> 3) * KST + (idx & 7) * 8]) = kpre[i];
            union { uint4 u; us s[8]; } uv; uv.u = vpre[i];
            int vr = idx & 63, va = (idx >> 6) * 8;
#pragma unroll
            for (int e = 0; e < 8; ++e) Vs[(va + e) * KST + vr] = uv.s[e];
        }
        // prefetch tile j+1 (latency hidden behind this tile's compute)
        if (j + 1 < nkt) {
#pragma unroll
            for (int i = 0; i < 2; ++i) {
                int idx = tid + i * 256;
                kpre[i] = *reinterpret_cast<const uint4*>(Kg + base + (size_t)((j + 1) * 64 + (idx >> 3)) * DH + (idx & 7) * 8);
                vpre[i] = *reinterpret_cast<const uint4*>(Vg + base + (size_t)((j + 1) * 64 + (idx & 63)) * DH + (idx >> 6) * 8);
            }
        }
        __syncthreads();   // tile j visible

        // S^T = K Q^T : rows = key (quad*4+reg within sub*16), col = m (l16)
        f32x4 s4[4];
#pragma unroll
        for (int sub = 0; sub < 4; ++sub) {
            bf16x8 k0 = *reinterpret_cast<const bf16x8*>(&Ks[(sub * 16 + l16) * KST + quad * 8]);
            bf16x8 k1 = *reinterpret_cast<const bf16x8*>(&Ks[(sub * 16 + l16) * KST + 32 + quad * 8]);
            f32x4 t = __builtin_amdgcn_mfma_f32_16x16x32_bf16(k0, qf0, zero4, 0, 0, 0);
            s4[sub]  = __builtin_amdgcn_mfma_f32_16x16x32_bf16(k1, qf1, t, 0, 0, 0);
        }

        // causal mask only on the diagonal tile
        if (j == qt) {
#pragma unroll
            for (int sub = 0; sub < 4; ++sub)
#pragma unroll
                for (int reg = 0; reg < 4; ++reg) {
                    int key = j * 64 + sub * 16 + quad * 4 + reg;
                    if (key > m) s4[sub][reg] = -INFINITY;
                }
        }

        // per-lane online softmax over this lane's 16 S values (log2 units)
        float mx = -INFINITY;
#pragma unroll
        for (int sub = 0; sub < 4; ++sub)
#pragma unroll
            for (int reg = 0; reg < 4; ++reg) mx = fmaxf(mx, s4[sub][reg]);
        mx = fmaxf(mx, __shfl_xor(mx, 16));
        mx = fmaxf(mx, __shfl_xor(mx, 32));
        float mnew  = fmaxf(mrow, mx);
        float alpha = exp2f(mrow - mnew);
        float rs = 0.f;
#pragma unroll
        for (int sub = 0; sub < 4; ++sub) {
            ushort4 pk;
            float p0 = exp2f(s4[sub][0] - mnew);
            float p1 = exp2f(s4[sub][1] - mnew);
            float p2 = exp2f(s4[sub][2] - mnew);
            float p3 = exp2f(s4[sub][3] - mnew);
            rs += (p0 + p1) + (p2 + p3);
            pk.x = f2bf(p0); pk.y = f2bf(p1); pk.z = f2bf(p2); pk.w = f2bf(p3);
            // P[m][key]: keys quad*4..+3 contiguous -> one 8B write
            *reinterpret_cast<ushort4*>(&Ps[wave][l16 * PST + sub * 16 + quad * 4]) = pk;
        }
        rs += __shfl_xor(rs, 16);
        rs += __shfl_xor(rs, 32);
        lrow = lrow * alpha + rs;
        mrow = mnew;
#pragma unroll
        for (int dsub = 0; dsub < 4; ++dsub) o[dsub] *= alpha;

        // O^T += V^T P : A = V^T[d][k] (Vs), B = P[m][k] (Ps); per-wave, no barrier
#pragma unroll
        for (int kc = 0; kc < 2; ++kc) {
            bf16x8 pf = *reinterpret_cast<const bf16x8*>(&Ps[wave][l16 * PST + kc * 32 + quad * 8]);
#pragma unroll
            for (int dsub = 0; dsub < 4; ++dsub) {
                bf16x8 vf = *reinterpret_cast<const bf16x8*>(&Vs[(dsub * 16 + l16) * KST + kc * 32 + quad * 8]);
                o[dsub] = __builtin_amdgcn_mfma_f32_16x16x32_bf16(vf, pf, o[dsub], 0, 0, 0);
            }
        }
    }

    // epilogue: O^T[d][m] -> att[b, t=m, h*64+d], bf16, 8B packed stores
    const int b = bh / NH, h = bh % NH;
    const float inv = 1.f / lrow;
    us* orow = Og + ((size_t)(b * TT + m)) * CC + h * DH;
#pragma unroll
    for (int dsub = 0; dsub < 4; ++dsub) {
        ushort4 pk;
        pk.x = f2bf(o[dsub][0] * inv);
        pk.y = f2bf(o[dsub][1] * inv);
        pk.z = f2bf(o[dsub][2] * inv);
        pk.w = f2bf(o[dsub][3] * inv);
        *reinterpret_cast<ushort4*>(orow + dsub * 16 + quad * 4) = pk;
    }
}

// ---------- launch ----------
extern "C" void kernel_launch(void* const* d_in, const int* in_sizes, int n_in,
                              void* d_out, int out_size, void* d_ws, size_t ws_size,
                              hipStream_t stream)
{
    const float* x      = (const float*)d_in[0];
    const float* w_attn = (const float*)d_in[1];
    const float* b_attn = (const float*)d_in[2];
    const float* w_proj = (const float*)d_in[3];
    const float* b_proj = (const float*)d_in[4];
    float* out = (float*)d_out;

    char* ws = (char*)d_ws;
    size_t off = 0;
    auto alloc = [&](size_t bytes) {
        void* p = ws + off;
        off += (bytes + 255) & ~(size_t)255;
        return p;
    };
    us* wtA = (us*)alloc((size_t)(3 * CC) * CC * 2);  // [2304][768] bf16
    us* wtP = (us*)alloc((size_t)CC * CC * 2);        // [768][768]  bf16
    us* xb  = (us*)alloc((size_t)MM * CC * 2);        // x as bf16
    us* Qb  = (us*)alloc((size_t)MM * CC * 2);        // [B,H,T,Dh]
    us* Kb  = (us*)alloc((size_t)MM * CC * 2);
    us* Vb  = (us*)alloc((size_t)MM * CC * 2);
    us* att = (us*)alloc((size_t)MM * CC * 2);        // [B,T,C]

    cast_k<<<1024, 256, 0, stream>>>(x, xb, MM * CC / 4);
    transpose_k<<<dim3((3 * CC) / 32, CC / 32), dim3(32, 8), 0, stream>>>(w_attn, wtA, CC, 3 * CC);
    transpose_k<<<dim3(CC / 32, CC / 32), dim3(32, 8), 0, stream>>>(w_proj, wtP, CC, CC);

    gemm_bt<1><<<dim3((3 * CC) / BN, MM / BM), 256, 0, stream>>>(
        xb, wtA, b_attn, nullptr, Qb, Kb, Vb, MM, 3 * CC, CC);

    attn_k<<<dim3(TT / 64, BB * NH), 256, 0, stream>>>(Qb, Kb, Vb, att);

    gemm_bt<0><<<dim3(CC / BN, MM / BM), 256, 0, stream>>>(
        att, wtP, b_proj, out, nullptr, nullptr, nullptr, MM, CC, CC);

    (void)in_sizes; (void)n_in; (void)out_size; (void)ws_size;
}